// Round 4
// baseline (393.994 us; speedup 1.0000x reference)
//
#include <hip/hip_runtime.h>
#include <hip/hip_bf16.h>
#include <cstdint>

// Problem constants
#define TT   32768
#define DD   256
#define KV   16      // K == V == 16
#define NBLK 2
#define HH   256
#define CH   64              // scan chunk length
#define NCH  (TT / CH)       // 512 chunks

typedef __attribute__((ext_vector_type(8))) short bf16x8;   // 8 bf16 in 4 VGPRs
typedef __attribute__((ext_vector_type(4))) float f32x4;

__device__ __forceinline__ float phi_f(float x)  { return x > 0.f ? x + 1.f : expf(x); }
__device__ __forceinline__ float lrelu_f(float x){ return x > 0.f ? x : 0.01f * x; }
__device__ __forceinline__ unsigned short f2bf(float f) {   // RNE f32->bf16
  unsigned u = __float_as_uint(f);
  u += 0x7fffu + ((u >> 16) & 1u);
  return (unsigned short)(u >> 16);
}
__device__ __forceinline__ float bf2f(unsigned short h) {
  return __uint_as_float(((unsigned)h) << 16);
}

// ---------------------------------------------------------------------------
// start-dtype detection (unchanged)
// ---------------------------------------------------------------------------
__global__ void k_detect(const void* __restrict__ startp, int* __restrict__ flags) {
  int stride = gridDim.x * blockDim.x;
  for (int t = blockIdx.x * blockDim.x + threadIdx.x; t < TT / 4; t += stride) {
    unsigned u = ((const unsigned*)startp)[t];
    if (u > 1u) atomicOr(&flags[0], 1);
    float f = ((const float*)startp)[t];
    if (!(f == 0.f || f == 1.f)) atomicOr(&flags[1], 1);
  }
}

__global__ void k_canon(const void* __restrict__ startp, const int* __restrict__ flags,
                        float* __restrict__ start_f) {
  int v32 = flags[0], vf = flags[1];
  int stride = gridDim.x * blockDim.x;
  for (int t = blockIdx.x * blockDim.x + threadIdx.x; t < TT; t += stride) {
    bool s;
    if (v32 == 0)     s = ((const unsigned*)startp)[t] != 0u;
    else if (vf == 0) s = ((const float*)startp)[t] != 0.f;
    else              s = ((const unsigned char*)startp)[t] != 0;
    start_f[t] = s ? 1.f : 0.f;
  }
}

// ---------------------------------------------------------------------------
// Weight conversions
// ---------------------------------------------------------------------------
__global__ __launch_bounds__(256) void k_cvtbig(
    const float* __restrict__ s0, const float* __restrict__ s1, const float* __restrict__ s2,
    unsigned short* __restrict__ d0, unsigned short* __restrict__ d1,
    unsigned short* __restrict__ d2, int n) {
  int i = (blockIdx.x * 256 + threadIdx.x) * 8;
  const float* s; unsigned short* d;
  if (i < n)            { s = s0; d = d0; }
  else if (i < 2 * n)   { s = s1; d = d1; i -= n; }
  else if (i < 3 * n)   { s = s2; d = d2; i -= 2 * n; }
  else return;
  float4 a = *(const float4*)(s + i);
  float4 b = *(const float4*)(s + i + 4);
  float vals[8] = {a.x, a.y, a.z, a.w, b.x, b.y, b.z, b.w};
  bf16x8 t;
#pragma unroll
  for (int j = 0; j < 8; j++) t[j] = (short)f2bf(vals[j]);
  *(bf16x8*)(d + i) = t;
}

__global__ __launch_bounds__(256) void k_cvtproj(
    const float* __restrict__ Wk, const float* __restrict__ Wq, const float* __restrict__ Wv,
    unsigned short* __restrict__ wh, unsigned short* __restrict__ wl) {
  int t8 = blockIdx.x * 256 + threadIdx.x;
  if (t8 >= NBLK * 48 * 256 / 8) return;
  int e = t8 * 8;
  int b = e / (48 * 256);
  int rem = e - b * 48 * 256;
  int o = rem / (16 * 256);
  int nr = rem - o * 16 * 256;
  const float* src = (o == 0 ? Wk : o == 1 ? Wq : Wv) + b * 16 * 256 + nr;
  float4 a = *(const float4*)src;
  float4 c = *(const float4*)(src + 4);
  float vals[8] = {a.x, a.y, a.z, a.w, c.x, c.y, c.z, c.w};
  bf16x8 th, tl;
#pragma unroll
  for (int j = 0; j < 8; j++) {
    unsigned short h = f2bf(vals[j]);
    th[j] = (short)h;
    tl[j] = (short)f2bf(vals[j] - bf2f(h));
  }
  *(bf16x8*)(wh + e) = th;
  *(bf16x8*)(wl + e) = tl;
}

// Wm1 [NB][256][16] -> hi/lo [NB][256][32] zero-padded in k (16..31 = 0)
__global__ __launch_bounds__(256) void k_cvtm1(
    const float* __restrict__ Wm1,
    unsigned short* __restrict__ h, unsigned short* __restrict__ l) {
  int row = blockIdx.x * 256 + threadIdx.x;
  if (row >= NBLK * 256) return;
  const float* s = Wm1 + row * 16;
  bf16x8 th0, tl0, th1, tl1, z;
#pragma unroll
  for (int j = 0; j < 8; j++) {
    float v0 = s[j], v1 = s[j + 8];
    unsigned short h0 = f2bf(v0), h1 = f2bf(v1);
    th0[j] = (short)h0; tl0[j] = (short)f2bf(v0 - bf2f(h0));
    th1[j] = (short)h1; tl1[j] = (short)f2bf(v1 - bf2f(h1));
    z[j] = 0;
  }
  unsigned short* dh = h + row * 32;
  unsigned short* dl = l + row * 32;
  *(bf16x8*)(dh) = th0;  *(bf16x8*)(dh + 8) = th1;
  *(bf16x8*)(dh + 16) = z; *(bf16x8*)(dh + 24) = z;
  *(bf16x8*)(dl) = tl0;  *(bf16x8*)(dl + 8) = tl1;
  *(bf16x8*)(dl + 16) = z; *(bf16x8*)(dl + 24) = z;
}

// x f32 [T][256] -> hi/lo bf16 planes
__global__ __launch_bounds__(256) void k_cvtx(const float* __restrict__ x,
                                              unsigned short* __restrict__ xh,
                                              unsigned short* __restrict__ xl) {
  size_t i = ((size_t)blockIdx.x * 256 + threadIdx.x) * 8;
  if (i >= (size_t)TT * DD) return;
  float4 a = *(const float4*)(x + i);
  float4 b = *(const float4*)(x + i + 4);
  float vals[8] = {a.x, a.y, a.z, a.w, b.x, b.y, b.z, b.w};
  bf16x8 th, tl;
#pragma unroll
  for (int j = 0; j < 8; j++) {
    unsigned short h = f2bf(vals[j]);
    th[j] = (short)h;
    tl[j] = (short)f2bf(vals[j] - bf2f(h));
  }
  *(bf16x8*)(xh + i) = th;
  *(bf16x8*)(xl + i) = tl;
}

// ---------------------------------------------------------------------------
// LDS-free MFMA projection: reads xbh/xbl direct from global as A-frags.
// Wave wv owns rows [wg*64+wv*16, +16); 72 MFMA/wave; no barriers.
// ---------------------------------------------------------------------------
__global__ __launch_bounds__(256) void k_proj3(
    const unsigned short* __restrict__ xbh, const unsigned short* __restrict__ xbl,
    const unsigned short* __restrict__ wh, const unsigned short* __restrict__ wl,
    const float* __restrict__ bv,
    float* __restrict__ kout, float* __restrict__ qout, float* __restrict__ vout) {
  int tid = threadIdx.x, wg = blockIdx.x;
  int lane = tid & 63, wv = tid >> 6, lg = lane >> 4, lr = lane & 15;
  size_t rbase = (size_t)wg * 64;
  int r = wv * 16 + lr;
  f32x4 acc[3];
#pragma unroll
  for (int o = 0; o < 3; o++) acc[o] = (f32x4){0.f, 0.f, 0.f, 0.f};

#pragma unroll
  for (int kk = 0; kk < 8; kk++) {
    size_t xo = (rbase + r) * DD + kk * 32 + lg * 8;
    bf16x8 ah = *(const bf16x8*)(xbh + xo);
    bf16x8 al = *(const bf16x8*)(xbl + xo);
    int kbyte = kk * 64 + lg * 16;
#pragma unroll
    for (int o = 0; o < 3; o++) {
      bf16x8 bh = *(const bf16x8*)((const char*)wh + (o * 16 + lr) * 512 + kbyte);
      bf16x8 bl = *(const bf16x8*)((const char*)wl + (o * 16 + lr) * 512 + kbyte);
      acc[o] = __builtin_amdgcn_mfma_f32_16x16x32_bf16(ah, bh, acc[o], 0, 0, 0);
      acc[o] = __builtin_amdgcn_mfma_f32_16x16x32_bf16(al, bh, acc[o], 0, 0, 0);
      acc[o] = __builtin_amdgcn_mfma_f32_16x16x32_bf16(ah, bl, acc[o], 0, 0, 0);
    }
  }
  float bvv = bv[lr];
#pragma unroll
  for (int rg = 0; rg < 4; rg++) {
    size_t g = rbase + wv * 16 + lg * 4 + rg;
    kout[g * KV + lr] = phi_f(acc[0][rg]);
    qout[g * KV + lr] = phi_f(acc[1][rg]);
    vout[g * KV + lr] = acc[2][rg] + bvv;
  }
}

// ---------------------------------------------------------------------------
// Per-chunk tails (unchanged)
// ---------------------------------------------------------------------------
__global__ __launch_bounds__(256) void k_tails(
    const float* __restrict__ k, const float* __restrict__ v,
    const float* __restrict__ start_f,
    float* __restrict__ tails_s, float* __restrict__ tails_zs,
    float* __restrict__ tails_flag) {
  __shared__ float kc[CH * KV], vc[CH * KV], stc[CH], red[CH];
  __shared__ int lsS;
  int c = blockIdx.x, tid = threadIdx.x;
  const float* kp = k + (size_t)c * CH * KV;
  const float* vp = v + (size_t)c * CH * KV;
  for (int u = tid; u < CH * KV; u += 256) { kc[u] = kp[u]; vc[u] = vp[u]; }
  if (tid < CH) stc[tid] = start_f[c * CH + tid];
  __syncthreads();
  if (tid == 0) {
    int ls = -1;
    for (int t = 0; t < CH; t++) if (stc[t] != 0.f) ls = t;
    lsS = ls;
  }
  __syncthreads();
  int ls = lsS;
  int t0 = ls < 0 ? 0 : ls;
  int i = tid >> 4, j = tid & 15;
  float s = 0.f;
  for (int t = t0; t < CH; t++) s += kc[t * KV + i] * vc[t * KV + j];
  tails_s[(size_t)c * 256 + tid] = s;
  if (tid < CH) {
    float r = 0.f;
    if (tid >= t0) {
      for (int i2 = 0; i2 < KV; i2++) r += kc[tid * KV + i2];
    }
    red[tid] = r;
  }
  __syncthreads();
  if (tid == 0) {
    float z = 0.f;
    for (int t = 0; t < CH; t++) z += red[t];
    tails_zs[c] = z;
    tails_flag[c] = (ls >= 0) ? 1.f : 0.f;
  }
}

// ---------------------------------------------------------------------------
// Attention core (S stride padded to 65: kills 16-way bank conflict in PV)
// ---------------------------------------------------------------------------
#define SP 65
__global__ __launch_bounds__(256) void k_att(
    const float* __restrict__ q, const float* __restrict__ k,
    const float* __restrict__ v, const float* __restrict__ start_f,
    const float* __restrict__ tails_s, const float* __restrict__ tails_zs,
    const float* __restrict__ tails_flag,
    const float* __restrict__ s0, const float* __restrict__ z0,
    float* __restrict__ att) {
  __shared__ float qc[CH * KV], kc[CH * KV], vc[CH * KV], stc[CH];
  __shared__ float S[CH * SP];
  __shared__ float carry[256];
  __shared__ float ksum[CH], zsl[CH], qsum[CH];
  __shared__ int ns[CH];
  __shared__ float czs_s;
  int c = blockIdx.x, tid = threadIdx.x;
  size_t base = (size_t)c * CH * KV;
  for (int u = tid; u < CH * KV; u += 256) {
    qc[u] = q[base + u]; kc[u] = k[base + u]; vc[u] = v[base + u];
  }
  if (tid < CH) stc[tid] = start_f[c * CH + tid];
  __syncthreads();
  if (tid < CH) {
    int cnt = 0;
    for (int u = 0; u <= tid; u++) cnt += (stc[u] != 0.f);
    ns[tid] = cnt;
    float ks = 0.f, qs = 0.f;
    for (int i = 0; i < KV; i++) { ks += kc[tid * KV + i]; qs += qc[tid * KV + i]; }
    ksum[tid] = ks; qsum[tid] = qs;
  }
  __syncthreads();
  if (tid < CH) {
    float acc = 0.f;
    for (int u = tid; u >= 0; u--) { acc += ksum[u]; if (stc[u] != 0.f) break; }
    zsl[tid] = acc;
  }
  {
    float accs = 0.f, aczs = 0.f;
    int cc = c - 1;
    for (;;) {
      if (cc < 0) {
        accs += s0[tid];
        if (tid == 0) { float z = 0.f; for (int i = 0; i < KV; i++) z += z0[i]; aczs += z; }
        break;
      }
      float fl = tails_flag[cc];
      accs += tails_s[(size_t)cc * 256 + tid];
      if (tid == 0) aczs += tails_zs[cc];
      if (fl != 0.f) break;
      cc--;
    }
    carry[tid] = accs;
    if (tid == 0) czs_s = aczs;
  }
  __syncthreads();
  {
    int t = tid >> 2, g = tid & 3;
    for (int u = 0; u < 16; u++) {
      int tp = g * 16 + u;
      float val = 0.f;
      if (tp <= t && ns[tp] == ns[t]) {
        float dot = 0.f;
        for (int i = 0; i < KV; i++) dot += qc[t * KV + i] * kc[tp * KV + i];
        val = dot;
      }
      S[t * SP + tp] = val;
    }
  }
  __syncthreads();
  float czs = czs_s;
  int j = tid & 15, tr = tid >> 4;
  for (int p = 0; p < 4; p++) {
    int t = p * 16 + tr;
    float numer = 0.f;
    for (int tp = 0; tp < CH; tp++) numer += S[t * SP + tp] * vc[tp * KV + j];
    float zs = zsl[t];
    if (ns[t] == 0) {
      float cn = 0.f;
      for (int i = 0; i < KV; i++) cn += qc[t * KV + i] * carry[i * KV + j];
      numer += cn;
      zs += czs;
    }
    float denom = fmaxf(zs * qsum[t], 1e-6f);
    att[base + t * KV + j] = numer / denom;
  }
}

// ---------------------------------------------------------------------------
// All-MFMA MLP + skip + LayerNorm. 40KB LDS -> 4 blocks/CU.
//   stage A: h1 = lrelu(att@Wm1^T+bm1) via MFMA (att hi/lo, K padded to 32)
//   stage B: h2 = lrelu(h1@Wm2^T+bm2); h2 overwrites h1's LDS buffer
//   stage C: hf = h2@Wm3^T + (xh+xl)@Wsk^T + biases (x direct from global)
//   LN in registers; WX: residual read/write of xbh/xbl in place.
// ---------------------------------------------------------------------------
template<int WY, int WX>
__global__ __launch_bounds__(256, 4) void k_mlp3(
    const float* __restrict__ att,
    unsigned short* __restrict__ xbh, unsigned short* __restrict__ xbl,
    const unsigned short* __restrict__ wm1h, const unsigned short* __restrict__ wm1l,
    const float* __restrict__ bm1,
    const unsigned short* __restrict__ Wm2b, const float* __restrict__ bm2,
    const unsigned short* __restrict__ Wm3b, const float* __restrict__ bm3,
    const unsigned short* __restrict__ Wskb, const float* __restrict__ bsk,
    const float* __restrict__ lnw, const float* __restrict__ lnb,
    float* __restrict__ yout) {
  __shared__ unsigned short hb[64 * 256];        // 32KB swizzled bf16 (h1 then h2)
  __shared__ __align__(16) char uni[8192];       // aoh/aol then LN scratch
  unsigned short* aoh = (unsigned short*)uni;    // [64][32] padded
  unsigned short* aol = aoh + 64 * 32;
  float* redS = (float*)uni;                     // [256] (after stage A)
  float* redQ = redS + 256;
  float* mrow = redQ + 256;                      // [64]
  float* irow = mrow + 64;

  int tid = threadIdx.x, wg = blockIdx.x;
  size_t rbase = (size_t)wg * 64;

  // load att -> hi/lo, zero-padded K 16..31
  for (int idx = tid; idx < 64 * 32; idx += 256) {
    int row = idx >> 5, col = idx & 31;
    float v = (col < 16) ? att[(rbase + row) * KV + col] : 0.f;
    unsigned short h = f2bf(v);
    aoh[idx] = h;
    aol[idx] = f2bf(v - bf2f(h));
  }
  __syncthreads();

  int lane = tid & 63, wv = tid >> 6, lg = lane >> 4, lr = lane & 15;
  int nc0 = wv * 64;

  f32x4 acc[4][4];
#pragma unroll
  for (int a = 0; a < 4; a++)
#pragma unroll
    for (int b = 0; b < 4; b++) acc[a][b] = (f32x4){0.f, 0.f, 0.f, 0.f};

  // ---- stage A (MFMA): h1
  {
    bf16x8 b1h[4], b1l[4];
#pragma unroll
    for (int nt = 0; nt < 4; nt++) {
      int n = nc0 + nt * 16 + lr;
      b1h[nt] = *(const bf16x8*)(wm1h + n * 32 + lg * 8);
      b1l[nt] = *(const bf16x8*)(wm1l + n * 32 + lg * 8);
    }
#pragma unroll
    for (int mt = 0; mt < 4; mt++) {
      int r = mt * 16 + lr;
      bf16x8 ah = *(bf16x8*)(aoh + r * 32 + lg * 8);
      bf16x8 al = *(bf16x8*)(aol + r * 32 + lg * 8);
#pragma unroll
      for (int nt = 0; nt < 4; nt++) {
        acc[mt][nt] = __builtin_amdgcn_mfma_f32_16x16x32_bf16(ah, b1h[nt], acc[mt][nt], 0, 0, 0);
        acc[mt][nt] = __builtin_amdgcn_mfma_f32_16x16x32_bf16(al, b1h[nt], acc[mt][nt], 0, 0, 0);
        acc[mt][nt] = __builtin_amdgcn_mfma_f32_16x16x32_bf16(ah, b1l[nt], acc[mt][nt], 0, 0, 0);
      }
    }
  }
  __syncthreads();   // aoh reads done (uni reused later)
  {
    float bm1v[4];
#pragma unroll
    for (int nt = 0; nt < 4; nt++) bm1v[nt] = bm1[nc0 + nt * 16 + lr];
#pragma unroll
    for (int mt = 0; mt < 4; mt++)
#pragma unroll
      for (int nt = 0; nt < 4; nt++)
#pragma unroll
        for (int rg = 0; rg < 4; rg++) {
          int r = mt * 16 + lg * 4 + rg;
          int cc = nc0 + nt * 16 + lr;
          *(unsigned short*)((char*)hb + r * 512 + ((cc * 2) ^ ((r & 7) << 4))) =
              f2bf(lrelu_f(acc[mt][nt][rg] + bm1v[nt]));
        }
  }
  __syncthreads();

  // ---- stage B (MFMA): h2 = lrelu(h1@Wm2^T+bm2)
#pragma unroll
  for (int a = 0; a < 4; a++)
#pragma unroll
    for (int b = 0; b < 4; b++) acc[a][b] = (f32x4){0.f, 0.f, 0.f, 0.f};
  for (int kk = 0; kk < 8; kk++) {
    int kbyte = kk * 64 + lg * 16;
    bf16x8 bfr[4];
#pragma unroll
    for (int nt = 0; nt < 4; nt++) {
      int n = nc0 + nt * 16 + lr;
      bfr[nt] = *(const bf16x8*)((const char*)Wm2b + n * 512 + kbyte);
    }
#pragma unroll
    for (int mt = 0; mt < 4; mt++) {
      int r = mt * 16 + lr;
      bf16x8 af = *(bf16x8*)((char*)hb + r * 512 + (kbyte ^ ((r & 7) << 4)));
#pragma unroll
      for (int nt = 0; nt < 4; nt++)
        acc[mt][nt] = __builtin_amdgcn_mfma_f32_16x16x32_bf16(af, bfr[nt], acc[mt][nt], 0, 0, 0);
    }
  }
  __syncthreads();   // all reads of h1 complete before overwrite
  {
    float bm2v[4];
#pragma unroll
    for (int nt = 0; nt < 4; nt++) bm2v[nt] = bm2[nc0 + nt * 16 + lr];
#pragma unroll
    for (int mt = 0; mt < 4; mt++)
#pragma unroll
      for (int nt = 0; nt < 4; nt++)
#pragma unroll
        for (int rg = 0; rg < 4; rg++) {
          int r = mt * 16 + lg * 4 + rg;
          int cc = nc0 + nt * 16 + lr;
          *(unsigned short*)((char*)hb + r * 512 + ((cc * 2) ^ ((r & 7) << 4))) =
              f2bf(lrelu_f(acc[mt][nt][rg] + bm2v[nt]));
        }
  }
  __syncthreads();

  // ---- stage C: hf = h2@Wm3^T + (xh+xl)@Wsk^T
  f32x4 acc2[4][4];
#pragma unroll
  for (int a = 0; a < 4; a++)
#pragma unroll
    for (int b = 0; b < 4; b++) acc2[a][b] = (f32x4){0.f, 0.f, 0.f, 0.f};
  for (int kk = 0; kk < 8; kk++) {
    int kbyte = kk * 64 + lg * 16;
    bf16x8 b3[4], bs[4];
#pragma unroll
    for (int nt = 0; nt < 4; nt++) {
      int n = nc0 + nt * 16 + lr;
      b3[nt] = *(const bf16x8*)((const char*)Wm3b + n * 512 + kbyte);
      bs[nt] = *(const bf16x8*)((const char*)Wskb + n * 512 + kbyte);
    }
#pragma unroll
    for (int mt = 0; mt < 4; mt++) {
      int r = mt * 16 + lr;
      bf16x8 a2 = *(bf16x8*)((char*)hb + r * 512 + (kbyte ^ ((r & 7) << 4)));
#pragma unroll
      for (int nt = 0; nt < 4; nt++)
        acc2[mt][nt] = __builtin_amdgcn_mfma_f32_16x16x32_bf16(a2, b3[nt], acc2[mt][nt], 0, 0, 0);
      size_t xo = (rbase + r) * DD + kk * 32 + lg * 8;
      bf16x8 xh8 = *(const bf16x8*)(xbh + xo);
#pragma unroll
      for (int nt = 0; nt < 4; nt++)
        acc2[mt][nt] = __builtin_amdgcn_mfma_f32_16x16x32_bf16(xh8, bs[nt], acc2[mt][nt], 0, 0, 0);
      bf16x8 xl8 = *(const bf16x8*)(xbl + xo);
#pragma unroll
      for (int nt = 0; nt < 4; nt++)
        acc2[mt][nt] = __builtin_amdgcn_mfma_f32_16x16x32_bf16(xl8, bs[nt], acc2[mt][nt], 0, 0, 0);
    }
  }
#pragma unroll
  for (int nt = 0; nt < 4; nt++) {
    int cc = nc0 + nt * 16 + lr;
    float bb = bm3[cc] + bsk[cc];
#pragma unroll
    for (int mt = 0; mt < 4; mt++)
#pragma unroll
      for (int rg = 0; rg < 4; rg++) acc2[mt][nt][rg] += bb;
  }

  // ---- LayerNorm stats in registers (redS/redQ live in uni)
#pragma unroll
  for (int mt = 0; mt < 4; mt++)
#pragma unroll
    for (int rg = 0; rg < 4; rg++) {
      float s = 0.f, q = 0.f;
#pragma unroll
      for (int nt = 0; nt < 4; nt++) {
        float v = acc2[mt][nt][rg];
        s += v; q += v * v;
      }
#pragma unroll
      for (int m = 1; m < 16; m <<= 1) {
        s += __shfl_xor(s, m);
        q += __shfl_xor(q, m);
      }
      if (lr == 0) {
        int r = mt * 16 + lg * 4 + rg;
        redS[wv * 64 + r] = s;
        redQ[wv * 64 + r] = q;
      }
    }
  __syncthreads();
  if (tid < 64) {
    float s = redS[tid] + redS[64 + tid] + redS[128 + tid] + redS[192 + tid];
    float q = redQ[tid] + redQ[64 + tid] + redQ[128 + tid] + redQ[192 + tid];
    float m = s * (1.f / 256.f);
    float var = q * (1.f / 256.f) - m * m;
    mrow[tid] = m;
    irow[tid] = rsqrtf(var + 1e-5f);
  }
  __syncthreads();

  // ---- normalize + store
  {
    float lnwv[4], lnbv[4];
#pragma unroll
    for (int nt = 0; nt < 4; nt++) {
      int cc = nc0 + nt * 16 + lr;
      lnwv[nt] = lnw[cc]; lnbv[nt] = lnb[cc];
    }
#pragma unroll
    for (int mt = 0; mt < 4; mt++)
#pragma unroll
      for (int rg = 0; rg < 4; rg++) {
        int r = mt * 16 + lg * 4 + rg;
        float m = mrow[r], is = irow[r];
        size_t gr = (rbase + r) * DD;
#pragma unroll
        for (int nt = 0; nt < 4; nt++) {
          int cc = nc0 + nt * 16 + lr;
          float y = (acc2[mt][nt][rg] - m) * is * lnwv[nt] + lnbv[nt];
          if (WY) yout[gr + cc] = y;
          if (WX) {
            size_t o = gr + cc;
            float xf = bf2f(xbh[o]) + bf2f(xbl[o]);
            float s = xf + y;
            unsigned short nh = f2bf(s);
            xbh[o] = nh;
            xbl[o] = f2bf(s - bf2f(nh));
          }
        }
      }
  }
}

// ---------------------------------------------------------------------------
extern "C" void kernel_launch(void* const* d_in, const int* in_sizes, int n_in,
                              void* d_out, int out_size, void* d_ws, size_t ws_size,
                              hipStream_t stream) {
  const float* x_in = (const float*)d_in[0];
  const void*  startp = d_in[1];
  const float* s0  = (const float*)d_in[2];
  const float* z0  = (const float*)d_in[3];
  const float* Wk  = (const float*)d_in[4];
  const float* Wq  = (const float*)d_in[5];
  const float* Wv  = (const float*)d_in[6];
  const float* bv  = (const float*)d_in[7];
  const float* Wsk = (const float*)d_in[8];
  const float* bsk = (const float*)d_in[9];
  const float* Wm1 = (const float*)d_in[10];
  const float* bm1 = (const float*)d_in[11];
  const float* Wm2 = (const float*)d_in[12];
  const float* bm2 = (const float*)d_in[13];
  const float* Wm3 = (const float*)d_in[14];
  const float* bm3 = (const float*)d_in[15];
  const float* lnw = (const float*)d_in[16];
  const float* lnb = (const float*)d_in[17];
  float* yout = (float*)d_out;

  float* ws = (float*)d_ws;
  int*   flags   = (int*)d_ws;
  float* start_f = ws + 16;
  float* kbuf    = start_f + TT;
  float* qbuf    = kbuf + (size_t)TT * KV;
  float* vbuf    = qbuf + (size_t)TT * KV;
  float* abuf    = vbuf + (size_t)TT * KV;
  float* ts      = abuf + (size_t)TT * KV;
  float* tz      = ts + (size_t)NCH * 256;
  float* tf      = tz + NCH;
  unsigned short* wm2b = (unsigned short*)(tf + NCH);
  unsigned short* wm3b = wm2b + (size_t)NBLK * HH * HH;
  unsigned short* wskb = wm3b + (size_t)NBLK * HH * HH;
  unsigned short* wpjh = wskb + (size_t)NBLK * HH * DD;     // [b][48][256] hi
  unsigned short* wpjl = wpjh + (size_t)NBLK * 48 * DD;     // [b][48][256] lo
  unsigned short* wm1h = wpjl + (size_t)NBLK * 48 * DD;     // [b][256][32]
  unsigned short* wm1l = wm1h + (size_t)NBLK * HH * 32;
  unsigned short* xbh  = wm1l + (size_t)NBLK * HH * 32;     // [T][256] hi
  unsigned short* xbl  = xbh + (size_t)TT * DD;             // [T][256] lo

  hipMemsetAsync(d_ws, 0, 64, stream);
  k_detect<<<64, 256, 0, stream>>>(startp, flags);
  k_canon<<<256, 256, 0, stream>>>(startp, flags, start_f);

  k_cvtbig<<<192, 256, 0, stream>>>(Wm2, Wm3, Wsk, wm2b, wm3b, wskb, NBLK * HH * HH);
  k_cvtproj<<<12, 256, 0, stream>>>(Wk, Wq, Wv, wpjh, wpjl);
  k_cvtm1<<<2, 256, 0, stream>>>(Wm1, wm1h, wm1l);
  k_cvtx<<<TT * DD / 8 / 256, 256, 0, stream>>>(x_in, xbh, xbl);

  for (int b = 0; b < NBLK; b++) {
    k_proj3<<<TT / 64, 256, 0, stream>>>(xbh, xbl,
        wpjh + (size_t)b * 48 * DD, wpjl + (size_t)b * 48 * DD,
        bv + (size_t)b * KV, kbuf, qbuf, vbuf);
    k_tails<<<NCH, 256, 0, stream>>>(kbuf, vbuf, start_f, ts, tz, tf);
    k_att<<<NCH, 256, 0, stream>>>(qbuf, kbuf, vbuf, start_f, ts, tz, tf,
        s0 + (size_t)b * 256, z0 + (size_t)b * KV, abuf);
    if (b == 0) {
      k_mlp3<0, 1><<<TT / 64, 256, 0, stream>>>(abuf, xbh, xbl,
          wm1h + (size_t)b * HH * 32, wm1l + (size_t)b * HH * 32, bm1 + (size_t)b * HH,
          wm2b + (size_t)b * HH * HH, bm2 + (size_t)b * HH,
          wm3b + (size_t)b * HH * HH, bm3 + (size_t)b * HH,
          wskb + (size_t)b * HH * DD, bsk + (size_t)b * HH,
          lnw + (size_t)b * HH, lnb + (size_t)b * HH, yout);
    } else {
      k_mlp3<1, 0><<<TT / 64, 256, 0, stream>>>(abuf, xbh, xbl,
          wm1h + (size_t)b * HH * 32, wm1l + (size_t)b * HH * 32, bm1 + (size_t)b * HH,
          wm2b + (size_t)b * HH * HH, bm2 + (size_t)b * HH,
          wm3b + (size_t)b * HH * HH, bm3 + (size_t)b * HH,
          wskb + (size_t)b * HH * DD, bsk + (size_t)b * HH,
          lnw + (size_t)b * HH, lnb + (size_t)b * HH, yout);
    }
  }
}

// Round 5
// 319.713 us; speedup vs baseline: 1.2323x; 1.2323x over previous
//
#include <hip/hip_runtime.h>
#include <hip/hip_bf16.h>
#include <cstdint>

// Problem constants
#define TT   32768
#define DD   256
#define KV   16      // K == V == 16
#define NBLK 2
#define HH   256
#define CH   64              // scan chunk length
#define NCH  (TT / CH)       // 512 chunks

typedef __attribute__((ext_vector_type(8))) short bf16x8;   // 8 bf16 in 4 VGPRs
typedef __attribute__((ext_vector_type(4))) float f32x4;

__device__ __forceinline__ float phi_f(float x)  { return x > 0.f ? x + 1.f : expf(x); }
__device__ __forceinline__ float lrelu_f(float x){ return x > 0.f ? x : 0.01f * x; }
__device__ __forceinline__ unsigned short f2bf(float f) {   // RNE f32->bf16
  unsigned u = __float_as_uint(f);
  u += 0x7fffu + ((u >> 16) & 1u);
  return (unsigned short)(u >> 16);
}
__device__ __forceinline__ float bf2f(unsigned short h) {
  return __uint_as_float(((unsigned)h) << 16);
}

// ---------------------------------------------------------------------------
// start-dtype detection (unchanged)
// ---------------------------------------------------------------------------
__global__ void k_detect(const void* __restrict__ startp, int* __restrict__ flags) {
  int stride = gridDim.x * blockDim.x;
  for (int t = blockIdx.x * blockDim.x + threadIdx.x; t < TT / 4; t += stride) {
    unsigned u = ((const unsigned*)startp)[t];
    if (u > 1u) atomicOr(&flags[0], 1);
    float f = ((const float*)startp)[t];
    if (!(f == 0.f || f == 1.f)) atomicOr(&flags[1], 1);
  }
}

__global__ void k_canon(const void* __restrict__ startp, const int* __restrict__ flags,
                        float* __restrict__ start_f) {
  int v32 = flags[0], vf = flags[1];
  int stride = gridDim.x * blockDim.x;
  for (int t = blockIdx.x * blockDim.x + threadIdx.x; t < TT; t += stride) {
    bool s;
    if (v32 == 0)     s = ((const unsigned*)startp)[t] != 0u;
    else if (vf == 0) s = ((const float*)startp)[t] != 0.f;
    else              s = ((const unsigned char*)startp)[t] != 0;
    start_f[t] = s ? 1.f : 0.f;
  }
}

// ---------------------------------------------------------------------------
// Weight conversions
// ---------------------------------------------------------------------------
__global__ __launch_bounds__(256) void k_cvtbig(
    const float* __restrict__ s0, const float* __restrict__ s1, const float* __restrict__ s2,
    unsigned short* __restrict__ d0, unsigned short* __restrict__ d1,
    unsigned short* __restrict__ d2, int n) {
  int i = (blockIdx.x * 256 + threadIdx.x) * 8;
  const float* s; unsigned short* d;
  if (i < n)            { s = s0; d = d0; }
  else if (i < 2 * n)   { s = s1; d = d1; i -= n; }
  else if (i < 3 * n)   { s = s2; d = d2; i -= 2 * n; }
  else return;
  float4 a = *(const float4*)(s + i);
  float4 b = *(const float4*)(s + i + 4);
  float vals[8] = {a.x, a.y, a.z, a.w, b.x, b.y, b.z, b.w};
  bf16x8 t;
#pragma unroll
  for (int j = 0; j < 8; j++) t[j] = (short)f2bf(vals[j]);
  *(bf16x8*)(d + i) = t;
}

__global__ __launch_bounds__(256) void k_cvtproj(
    const float* __restrict__ Wk, const float* __restrict__ Wq, const float* __restrict__ Wv,
    unsigned short* __restrict__ wh, unsigned short* __restrict__ wl) {
  int t8 = blockIdx.x * 256 + threadIdx.x;
  if (t8 >= NBLK * 48 * 256 / 8) return;
  int e = t8 * 8;
  int b = e / (48 * 256);
  int rem = e - b * 48 * 256;
  int o = rem / (16 * 256);
  int nr = rem - o * 16 * 256;
  const float* src = (o == 0 ? Wk : o == 1 ? Wq : Wv) + b * 16 * 256 + nr;
  float4 a = *(const float4*)src;
  float4 c = *(const float4*)(src + 4);
  float vals[8] = {a.x, a.y, a.z, a.w, c.x, c.y, c.z, c.w};
  bf16x8 th, tl;
#pragma unroll
  for (int j = 0; j < 8; j++) {
    unsigned short h = f2bf(vals[j]);
    th[j] = (short)h;
    tl[j] = (short)f2bf(vals[j] - bf2f(h));
  }
  *(bf16x8*)(wh + e) = th;
  *(bf16x8*)(wl + e) = tl;
}

// Wm1 [NB][256][16] -> hi/lo [NB][256][32] zero-padded in k (16..31 = 0)
__global__ __launch_bounds__(256) void k_cvtm1(
    const float* __restrict__ Wm1,
    unsigned short* __restrict__ h, unsigned short* __restrict__ l) {
  int row = blockIdx.x * 256 + threadIdx.x;
  if (row >= NBLK * 256) return;
  const float* s = Wm1 + row * 16;
  bf16x8 th0, tl0, th1, tl1, z;
#pragma unroll
  for (int j = 0; j < 8; j++) {
    float v0 = s[j], v1 = s[j + 8];
    unsigned short h0 = f2bf(v0), h1 = f2bf(v1);
    th0[j] = (short)h0; tl0[j] = (short)f2bf(v0 - bf2f(h0));
    th1[j] = (short)h1; tl1[j] = (short)f2bf(v1 - bf2f(h1));
    z[j] = 0;
  }
  unsigned short* dh = h + row * 32;
  unsigned short* dl = l + row * 32;
  *(bf16x8*)(dh) = th0;  *(bf16x8*)(dh + 8) = th1;
  *(bf16x8*)(dh + 16) = z; *(bf16x8*)(dh + 24) = z;
  *(bf16x8*)(dl) = tl0;  *(bf16x8*)(dl + 8) = tl1;
  *(bf16x8*)(dl + 16) = z; *(bf16x8*)(dl + 24) = z;
}

// ---------------------------------------------------------------------------
// MFMA projection (round-3 proven): x f32 staged in LDS as split bf16 hi/lo.
// ---------------------------------------------------------------------------
__global__ __launch_bounds__(256) void k_proj2(
    const float* __restrict__ x,
    const unsigned short* __restrict__ wh, const unsigned short* __restrict__ wl,
    const float* __restrict__ bv,
    float* __restrict__ kout, float* __restrict__ qout, float* __restrict__ vout) {
  __shared__ unsigned short xh[64 * 256];   // 32 KB swizzled
  __shared__ unsigned short xl[64 * 256];   // 32 KB swizzled
  int tid = threadIdx.x, wg = blockIdx.x;
  size_t rbase = (size_t)wg * 64;
  const float* xs = x + rbase * DD;
#pragma unroll
  for (int i = 0; i < 8; i++) {
    int idx = tid + i * 256;
    int row = idx >> 5, c8 = idx & 31;
    const float* p = xs + row * DD + c8 * 8;
    float4 a = *(const float4*)p;
    float4 b = *(const float4*)(p + 4);
    float vals[8] = {a.x, a.y, a.z, a.w, b.x, b.y, b.z, b.w};
    bf16x8 th, tl;
#pragma unroll
    for (int j = 0; j < 8; j++) {
      unsigned short h = f2bf(vals[j]);
      th[j] = (short)h;
      tl[j] = (short)f2bf(vals[j] - bf2f(h));
    }
    int off = row * 512 + ((c8 * 16) ^ ((row & 7) << 4));
    *(bf16x8*)((char*)xh + off) = th;
    *(bf16x8*)((char*)xl + off) = tl;
  }
  __syncthreads();

  int lane = tid & 63, wv = tid >> 6, lg = lane >> 4, lr = lane & 15;
  int r = wv * 16 + lr;
  f32x4 acc[3];
#pragma unroll
  for (int o = 0; o < 3; o++) acc[o] = (f32x4){0.f, 0.f, 0.f, 0.f};

#pragma unroll
  for (int kk = 0; kk < 8; kk++) {
    int kbyte = kk * 64 + lg * 16;
    int off = r * 512 + (kbyte ^ ((r & 7) << 4));
    bf16x8 ah = *(bf16x8*)((char*)xh + off);
    bf16x8 al = *(bf16x8*)((char*)xl + off);
#pragma unroll
    for (int o = 0; o < 3; o++) {
      bf16x8 bh = *(const bf16x8*)((const char*)wh + (o * 16 + lr) * 512 + kbyte);
      bf16x8 bl = *(const bf16x8*)((const char*)wl + (o * 16 + lr) * 512 + kbyte);
      acc[o] = __builtin_amdgcn_mfma_f32_16x16x32_bf16(ah, bh, acc[o], 0, 0, 0);
      acc[o] = __builtin_amdgcn_mfma_f32_16x16x32_bf16(al, bh, acc[o], 0, 0, 0);
      acc[o] = __builtin_amdgcn_mfma_f32_16x16x32_bf16(ah, bl, acc[o], 0, 0, 0);
    }
  }
  float bvv = bv[lr];
#pragma unroll
  for (int rg = 0; rg < 4; rg++) {
    size_t g = rbase + wv * 16 + lg * 4 + rg;
    kout[g * KV + lr] = phi_f(acc[0][rg]);
    qout[g * KV + lr] = phi_f(acc[1][rg]);
    vout[g * KV + lr] = acc[2][rg] + bvv;
  }
}

// ---------------------------------------------------------------------------
// Per-chunk tails (unchanged)
// ---------------------------------------------------------------------------
__global__ __launch_bounds__(256) void k_tails(
    const float* __restrict__ k, const float* __restrict__ v,
    const float* __restrict__ start_f,
    float* __restrict__ tails_s, float* __restrict__ tails_zs,
    float* __restrict__ tails_flag) {
  __shared__ float kc[CH * KV], vc[CH * KV], stc[CH], red[CH];
  __shared__ int lsS;
  int c = blockIdx.x, tid = threadIdx.x;
  const float* kp = k + (size_t)c * CH * KV;
  const float* vp = v + (size_t)c * CH * KV;
  for (int u = tid; u < CH * KV; u += 256) { kc[u] = kp[u]; vc[u] = vp[u]; }
  if (tid < CH) stc[tid] = start_f[c * CH + tid];
  __syncthreads();
  if (tid == 0) {
    int ls = -1;
    for (int t = 0; t < CH; t++) if (stc[t] != 0.f) ls = t;
    lsS = ls;
  }
  __syncthreads();
  int ls = lsS;
  int t0 = ls < 0 ? 0 : ls;
  int i = tid >> 4, j = tid & 15;
  float s = 0.f;
  for (int t = t0; t < CH; t++) s += kc[t * KV + i] * vc[t * KV + j];
  tails_s[(size_t)c * 256 + tid] = s;
  if (tid < CH) {
    float r = 0.f;
    if (tid >= t0) {
      for (int i2 = 0; i2 < KV; i2++) r += kc[tid * KV + i2];
    }
    red[tid] = r;
  }
  __syncthreads();
  if (tid == 0) {
    float z = 0.f;
    for (int t = 0; t < CH; t++) z += red[t];
    tails_zs[c] = z;
    tails_flag[c] = (ls >= 0) ? 1.f : 0.f;
  }
}

// ---------------------------------------------------------------------------
// Attention core (S stride 65: conflict-free PV reads)
// ---------------------------------------------------------------------------
#define SP 65
__global__ __launch_bounds__(256) void k_att(
    const float* __restrict__ q, const float* __restrict__ k,
    const float* __restrict__ v, const float* __restrict__ start_f,
    const float* __restrict__ tails_s, const float* __restrict__ tails_zs,
    const float* __restrict__ tails_flag,
    const float* __restrict__ s0, const float* __restrict__ z0,
    float* __restrict__ att) {
  __shared__ float qc[CH * KV], kc[CH * KV], vc[CH * KV], stc[CH];
  __shared__ float S[CH * SP];
  __shared__ float carry[256];
  __shared__ float ksum[CH], zsl[CH], qsum[CH];
  __shared__ int ns[CH];
  __shared__ float czs_s;
  int c = blockIdx.x, tid = threadIdx.x;
  size_t base = (size_t)c * CH * KV;
  for (int u = tid; u < CH * KV; u += 256) {
    qc[u] = q[base + u]; kc[u] = k[base + u]; vc[u] = v[base + u];
  }
  if (tid < CH) stc[tid] = start_f[c * CH + tid];
  __syncthreads();
  if (tid < CH) {
    int cnt = 0;
    for (int u = 0; u <= tid; u++) cnt += (stc[u] != 0.f);
    ns[tid] = cnt;
    float ks = 0.f, qs = 0.f;
    for (int i = 0; i < KV; i++) { ks += kc[tid * KV + i]; qs += qc[tid * KV + i]; }
    ksum[tid] = ks; qsum[tid] = qs;
  }
  __syncthreads();
  if (tid < CH) {
    float acc = 0.f;
    for (int u = tid; u >= 0; u--) { acc += ksum[u]; if (stc[u] != 0.f) break; }
    zsl[tid] = acc;
  }
  {
    float accs = 0.f, aczs = 0.f;
    int cc = c - 1;
    for (;;) {
      if (cc < 0) {
        accs += s0[tid];
        if (tid == 0) { float z = 0.f; for (int i = 0; i < KV; i++) z += z0[i]; aczs += z; }
        break;
      }
      float fl = tails_flag[cc];
      accs += tails_s[(size_t)cc * 256 + tid];
      if (tid == 0) aczs += tails_zs[cc];
      if (fl != 0.f) break;
      cc--;
    }
    carry[tid] = accs;
    if (tid == 0) czs_s = aczs;
  }
  __syncthreads();
  {
    int t = tid >> 2, g = tid & 3;
    for (int u = 0; u < 16; u++) {
      int tp = g * 16 + u;
      float val = 0.f;
      if (tp <= t && ns[tp] == ns[t]) {
        float dot = 0.f;
        for (int i = 0; i < KV; i++) dot += qc[t * KV + i] * kc[tp * KV + i];
        val = dot;
      }
      S[t * SP + tp] = val;
    }
  }
  __syncthreads();
  float czs = czs_s;
  int j = tid & 15, tr = tid >> 4;
  for (int p = 0; p < 4; p++) {
    int t = p * 16 + tr;
    float numer = 0.f;
    for (int tp = 0; tp < CH; tp++) numer += S[t * SP + tp] * vc[tp * KV + j];
    float zs = zsl[t];
    if (ns[t] == 0) {
      float cn = 0.f;
      for (int i = 0; i < KV; i++) cn += qc[t * KV + i] * carry[i * KV + j];
      numer += cn;
      zs += czs;
    }
    float denom = fmaxf(zs * qsum[t], 1e-6f);
    att[base + t * KV + j] = numer / denom;
  }
}

// ---------------------------------------------------------------------------
// All-MFMA MLP + skip + LayerNorm. 8 waves/block (512 thr), wave owns 64x32.
//   stage A: h1 = lrelu(att@Wm1^T+bm1), MFMA, att hi/lo in LDS (K pad 32)
//   stage B: h2 = lrelu(h1@Wm2^T+bm2); h2 overwrites h1 LDS buffer
//   stage C: hf = h2@Wm3^T + x@Wsk^T + biases (x f32 from global, cvt in reg)
//   LN in registers; f32 coalesced stores only (no write amplification).
// ---------------------------------------------------------------------------
#define A1S 40   // padded row stride (shorts) for att hi/lo staging
template<int WY, int WX>
__global__ __launch_bounds__(512, 4) void k_mlp4(
    const float* __restrict__ att, const float* __restrict__ xsrc,
    const unsigned short* __restrict__ wm1h, const unsigned short* __restrict__ wm1l,
    const float* __restrict__ bm1,
    const unsigned short* __restrict__ Wm2b, const float* __restrict__ bm2,
    const unsigned short* __restrict__ Wm3b, const float* __restrict__ bm3,
    const unsigned short* __restrict__ Wskb, const float* __restrict__ bsk,
    const float* __restrict__ lnw, const float* __restrict__ lnb,
    float* __restrict__ yout, float* __restrict__ xnext) {
  __shared__ unsigned short hb[64 * 256];        // 32KB swizzled bf16 (h1 then h2)
  __shared__ __align__(16) char uni[64 * A1S * 4];  // aoh/aol, later LN scratch
  unsigned short* aoh = (unsigned short*)uni;    // [64][A1S]
  unsigned short* aol = aoh + 64 * A1S;
  float* redS = (float*)uni;                     // [512]
  float* redQ = redS + 512;
  float* mrow = redQ + 512;                      // [64]
  float* irow = mrow + 64;

  int tid = threadIdx.x, wg = blockIdx.x;
  size_t rbase = (size_t)wg * 64;

  // load att -> hi/lo, K zero-padded 16..31
  for (int idx = tid; idx < 64 * 32; idx += 512) {
    int row = idx >> 5, col = idx & 31;
    float v = (col < 16) ? att[(rbase + row) * KV + col] : 0.f;
    unsigned short h = f2bf(v);
    aoh[row * A1S + col] = h;
    aol[row * A1S + col] = f2bf(v - bf2f(h));
  }
  __syncthreads();

  int lane = tid & 63, wv = tid >> 6, lg = lane >> 4, lr = lane & 15;
  int nc0 = wv * 32;          // wave's 32-column slice

  f32x4 acc[4][2];
#pragma unroll
  for (int a = 0; a < 4; a++)
#pragma unroll
    for (int b = 0; b < 2; b++) acc[a][b] = (f32x4){0.f, 0.f, 0.f, 0.f};

  // ---- stage A (MFMA): h1
  {
    bf16x8 b1h[2], b1l[2];
#pragma unroll
    for (int nt = 0; nt < 2; nt++) {
      int n = nc0 + nt * 16 + lr;
      b1h[nt] = *(const bf16x8*)(wm1h + n * 32 + lg * 8);
      b1l[nt] = *(const bf16x8*)(wm1l + n * 32 + lg * 8);
    }
#pragma unroll
    for (int mt = 0; mt < 4; mt++) {
      int r = mt * 16 + lr;
      bf16x8 ah = *(bf16x8*)(aoh + r * A1S + lg * 8);
      bf16x8 al = *(bf16x8*)(aol + r * A1S + lg * 8);
#pragma unroll
      for (int nt = 0; nt < 2; nt++) {
        acc[mt][nt] = __builtin_amdgcn_mfma_f32_16x16x32_bf16(ah, b1h[nt], acc[mt][nt], 0, 0, 0);
        acc[mt][nt] = __builtin_amdgcn_mfma_f32_16x16x32_bf16(al, b1h[nt], acc[mt][nt], 0, 0, 0);
        acc[mt][nt] = __builtin_amdgcn_mfma_f32_16x16x32_bf16(ah, b1l[nt], acc[mt][nt], 0, 0, 0);
      }
    }
  }
  __syncthreads();   // aoh/aol reads done (uni reused for LN later)
  {
    float bm1v[2];
#pragma unroll
    for (int nt = 0; nt < 2; nt++) bm1v[nt] = bm1[nc0 + nt * 16 + lr];
#pragma unroll
    for (int mt = 0; mt < 4; mt++)
#pragma unroll
      for (int nt = 0; nt < 2; nt++)
#pragma unroll
        for (int rg = 0; rg < 4; rg++) {
          int r = mt * 16 + lg * 4 + rg;
          int cc = nc0 + nt * 16 + lr;
          *(unsigned short*)((char*)hb + r * 512 + ((cc * 2) ^ ((r & 7) << 4))) =
              f2bf(lrelu_f(acc[mt][nt][rg] + bm1v[nt]));
        }
  }
  __syncthreads();

  // ---- stage B (MFMA): h2 = lrelu(h1@Wm2^T+bm2)
#pragma unroll
  for (int a = 0; a < 4; a++)
#pragma unroll
    for (int b = 0; b < 2; b++) acc[a][b] = (f32x4){0.f, 0.f, 0.f, 0.f};
  for (int kk = 0; kk < 8; kk++) {
    int kbyte = kk * 64 + lg * 16;
    bf16x8 bfr[2];
#pragma unroll
    for (int nt = 0; nt < 2; nt++) {
      int n = nc0 + nt * 16 + lr;
      bfr[nt] = *(const bf16x8*)((const char*)Wm2b + n * 512 + kbyte);
    }
#pragma unroll
    for (int mt = 0; mt < 4; mt++) {
      int r = mt * 16 + lr;
      bf16x8 af = *(bf16x8*)((char*)hb + r * 512 + (kbyte ^ ((r & 7) << 4)));
#pragma unroll
      for (int nt = 0; nt < 2; nt++)
        acc[mt][nt] = __builtin_amdgcn_mfma_f32_16x16x32_bf16(af, bfr[nt], acc[mt][nt], 0, 0, 0);
    }
  }
  __syncthreads();   // all reads of h1 complete before overwrite
  {
    float bm2v[2];
#pragma unroll
    for (int nt = 0; nt < 2; nt++) bm2v[nt] = bm2[nc0 + nt * 16 + lr];
#pragma unroll
    for (int mt = 0; mt < 4; mt++)
#pragma unroll
      for (int nt = 0; nt < 2; nt++)
#pragma unroll
        for (int rg = 0; rg < 4; rg++) {
          int r = mt * 16 + lg * 4 + rg;
          int cc = nc0 + nt * 16 + lr;
          *(unsigned short*)((char*)hb + r * 512 + ((cc * 2) ^ ((r & 7) << 4))) =
              f2bf(lrelu_f(acc[mt][nt][rg] + bm2v[nt]));
        }
  }
  __syncthreads();

  // ---- stage C: hf = h2@Wm3^T + x@Wsk^T
  f32x4 acc2[4][2];
#pragma unroll
  for (int a = 0; a < 4; a++)
#pragma unroll
    for (int b = 0; b < 2; b++) acc2[a][b] = (f32x4){0.f, 0.f, 0.f, 0.f};
  const float* xrow = xsrc + rbase * DD;
  for (int kk = 0; kk < 8; kk++) {
    int kbyte = kk * 64 + lg * 16;
    int kf = kk * 32 + lg * 8;
    bf16x8 b3[2], bs[2];
#pragma unroll
    for (int nt = 0; nt < 2; nt++) {
      int n = nc0 + nt * 16 + lr;
      b3[nt] = *(const bf16x8*)((const char*)Wm3b + n * 512 + kbyte);
      bs[nt] = *(const bf16x8*)((const char*)Wskb + n * 512 + kbyte);
    }
#pragma unroll
    for (int mt = 0; mt < 4; mt++) {
      int r = mt * 16 + lr;
      bf16x8 a2 = *(bf16x8*)((char*)hb + r * 512 + (kbyte ^ ((r & 7) << 4)));
#pragma unroll
      for (int nt = 0; nt < 2; nt++)
        acc2[mt][nt] = __builtin_amdgcn_mfma_f32_16x16x32_bf16(a2, b3[nt], acc2[mt][nt], 0, 0, 0);
      const float* xp = xrow + r * DD + kf;
      float4 x0 = *(const float4*)xp;
      float4 x1 = *(const float4*)(xp + 4);
      bf16x8 xv;
      xv[0] = (short)f2bf(x0.x); xv[1] = (short)f2bf(x0.y);
      xv[2] = (short)f2bf(x0.z); xv[3] = (short)f2bf(x0.w);
      xv[4] = (short)f2bf(x1.x); xv[5] = (short)f2bf(x1.y);
      xv[6] = (short)f2bf(x1.z); xv[7] = (short)f2bf(x1.w);
#pragma unroll
      for (int nt = 0; nt < 2; nt++)
        acc2[mt][nt] = __builtin_amdgcn_mfma_f32_16x16x32_bf16(xv, bs[nt], acc2[mt][nt], 0, 0, 0);
    }
  }
#pragma unroll
  for (int nt = 0; nt < 2; nt++) {
    int cc = nc0 + nt * 16 + lr;
    float bb = bm3[cc] + bsk[cc];
#pragma unroll
    for (int mt = 0; mt < 4; mt++)
#pragma unroll
      for (int rg = 0; rg < 4; rg++) acc2[mt][nt][rg] += bb;
  }

  // ---- LayerNorm stats in registers
#pragma unroll
  for (int mt = 0; mt < 4; mt++)
#pragma unroll
    for (int rg = 0; rg < 4; rg++) {
      float s = 0.f, q = 0.f;
#pragma unroll
      for (int nt = 0; nt < 2; nt++) {
        float v = acc2[mt][nt][rg];
        s += v; q += v * v;
      }
#pragma unroll
      for (int m = 1; m < 16; m <<= 1) {
        s += __shfl_xor(s, m);
        q += __shfl_xor(q, m);
      }
      if (lr == 0) {
        int r = mt * 16 + lg * 4 + rg;
        redS[wv * 64 + r] = s;
        redQ[wv * 64 + r] = q;
      }
    }
  __syncthreads();
  if (tid < 64) {
    float s = 0.f, q = 0.f;
#pragma unroll
    for (int w = 0; w < 8; w++) { s += redS[w * 64 + tid]; q += redQ[w * 64 + tid]; }
    float m = s * (1.f / 256.f);
    float var = q * (1.f / 256.f) - m * m;
    mrow[tid] = m;
    irow[tid] = rsqrtf(var + 1e-5f);
  }
  __syncthreads();

  // ---- normalize + store (f32 coalesced only)
  {
    float lnwv[2], lnbv[2];
#pragma unroll
    for (int nt = 0; nt < 2; nt++) {
      int cc = nc0 + nt * 16 + lr;
      lnwv[nt] = lnw[cc]; lnbv[nt] = lnb[cc];
    }
#pragma unroll
    for (int mt = 0; mt < 4; mt++)
#pragma unroll
      for (int rg = 0; rg < 4; rg++) {
        int r = mt * 16 + lg * 4 + rg;
        float m = mrow[r], is = irow[r];
        size_t gr = (rbase + r) * DD;
#pragma unroll
        for (int nt = 0; nt < 2; nt++) {
          int cc = nc0 + nt * 16 + lr;
          float y = (acc2[mt][nt][rg] - m) * is * lnwv[nt] + lnbv[nt];
          if (WY) yout[gr + cc] = y;
          if (WX) xnext[gr + cc] = xsrc[gr + cc] + y;
        }
      }
  }
}

// ---------------------------------------------------------------------------
extern "C" void kernel_launch(void* const* d_in, const int* in_sizes, int n_in,
                              void* d_out, int out_size, void* d_ws, size_t ws_size,
                              hipStream_t stream) {
  const float* x_in = (const float*)d_in[0];
  const void*  startp = d_in[1];
  const float* s0  = (const float*)d_in[2];
  const float* z0  = (const float*)d_in[3];
  const float* Wk  = (const float*)d_in[4];
  const float* Wq  = (const float*)d_in[5];
  const float* Wv  = (const float*)d_in[6];
  const float* bv  = (const float*)d_in[7];
  const float* Wsk = (const float*)d_in[8];
  const float* bsk = (const float*)d_in[9];
  const float* Wm1 = (const float*)d_in[10];
  const float* bm1 = (const float*)d_in[11];
  const float* Wm2 = (const float*)d_in[12];
  const float* bm2 = (const float*)d_in[13];
  const float* Wm3 = (const float*)d_in[14];
  const float* bm3 = (const float*)d_in[15];
  const float* lnw = (const float*)d_in[16];
  const float* lnb = (const float*)d_in[17];
  float* yout = (float*)d_out;

  float* ws = (float*)d_ws;
  int*   flags   = (int*)d_ws;
  float* start_f = ws + 16;
  float* kbuf    = start_f + TT;
  float* qbuf    = kbuf + (size_t)TT * KV;
  float* vbuf    = qbuf + (size_t)TT * KV;
  float* abuf    = vbuf + (size_t)TT * KV;
  float* ts      = abuf + (size_t)TT * KV;
  float* tz      = ts + (size_t)NCH * 256;
  float* tf      = tz + NCH;
  float* xcur    = tf + NCH;                                // T*D f32
  unsigned short* wm2b = (unsigned short*)(xcur + (size_t)TT * DD);
  unsigned short* wm3b = wm2b + (size_t)NBLK * HH * HH;
  unsigned short* wskb = wm3b + (size_t)NBLK * HH * HH;
  unsigned short* wpjh = wskb + (size_t)NBLK * HH * DD;     // [b][48][256] hi
  unsigned short* wpjl = wpjh + (size_t)NBLK * 48 * DD;     // [b][48][256] lo
  unsigned short* wm1h = wpjl + (size_t)NBLK * 48 * DD;     // [b][256][32]
  unsigned short* wm1l = wm1h + (size_t)NBLK * HH * 32;

  hipMemsetAsync(d_ws, 0, 64, stream);
  k_detect<<<64, 256, 0, stream>>>(startp, flags);
  k_canon<<<256, 256, 0, stream>>>(startp, flags, start_f);

  k_cvtbig<<<192, 256, 0, stream>>>(Wm2, Wm3, Wsk, wm2b, wm3b, wskb, NBLK * HH * HH);
  k_cvtproj<<<12, 256, 0, stream>>>(Wk, Wq, Wv, wpjh, wpjl);
  k_cvtm1<<<2, 256, 0, stream>>>(Wm1, wm1h, wm1l);

  const float* xs = x_in;
  for (int b = 0; b < NBLK; b++) {
    k_proj2<<<TT / 64, 256, 0, stream>>>(xs,
        wpjh + (size_t)b * 48 * DD, wpjl + (size_t)b * 48 * DD,
        bv + (size_t)b * KV, kbuf, qbuf, vbuf);
    k_tails<<<NCH, 256, 0, stream>>>(kbuf, vbuf, start_f, ts, tz, tf);
    k_att<<<NCH, 256, 0, stream>>>(qbuf, kbuf, vbuf, start_f, ts, tz, tf,
        s0 + (size_t)b * 256, z0 + (size_t)b * KV, abuf);
    if (b == 0) {
      k_mlp4<0, 1><<<TT / 64, 512, 0, stream>>>(abuf, xs,
          wm1h + (size_t)b * HH * 32, wm1l + (size_t)b * HH * 32, bm1 + (size_t)b * HH,
          wm2b + (size_t)b * HH * HH, bm2 + (size_t)b * HH,
          wm3b + (size_t)b * HH * HH, bm3 + (size_t)b * HH,
          wskb + (size_t)b * HH * DD, bsk + (size_t)b * HH,
          lnw + (size_t)b * HH, lnb + (size_t)b * HH, yout, xcur);
    } else {
      k_mlp4<1, 0><<<TT / 64, 512, 0, stream>>>(abuf, xs,
          wm1h + (size_t)b * HH * 32, wm1l + (size_t)b * HH * 32, bm1 + (size_t)b * HH,
          wm2b + (size_t)b * HH * HH, bm2 + (size_t)b * HH,
          wm3b + (size_t)b * HH * HH, bm3 + (size_t)b * HH,
          wskb + (size_t)b * HH * DD, bsk + (size_t)b * HH,
          lnw + (size_t)b * HH, lnb + (size_t)b * HH, yout, xcur);
    }
    xs = xcur;
  }
}

// Round 6
// 289.605 us; speedup vs baseline: 1.3605x; 1.1040x over previous
//
#include <hip/hip_runtime.h>
#include <hip/hip_bf16.h>
#include <cstdint>

// Problem constants
#define TT   32768
#define DD   256
#define KV   16      // K == V == 16
#define NBLK 2
#define HH   256
#define CH   64              // scan chunk length
#define NCH  (TT / CH)       // 512 chunks

typedef __attribute__((ext_vector_type(8))) short bf16x8;   // 8 bf16 in 4 VGPRs
typedef __attribute__((ext_vector_type(4))) float f32x4;

__device__ __forceinline__ float phi_f(float x)  { return x > 0.f ? x + 1.f : expf(x); }
__device__ __forceinline__ float lrelu_f(float x){ return x > 0.f ? x : 0.01f * x; }
__device__ __forceinline__ unsigned short f2bf(float f) {   // RNE f32->bf16
  unsigned u = __float_as_uint(f);
  u += 0x7fffu + ((u >> 16) & 1u);
  return (unsigned short)(u >> 16);
}
__device__ __forceinline__ float bf2f(unsigned short h) {
  return __uint_as_float(((unsigned)h) << 16);
}

// ---------------------------------------------------------------------------
// start-dtype detection (unchanged)
// ---------------------------------------------------------------------------
__global__ void k_detect(const void* __restrict__ startp, int* __restrict__ flags) {
  int stride = gridDim.x * blockDim.x;
  for (int t = blockIdx.x * blockDim.x + threadIdx.x; t < TT / 4; t += stride) {
    unsigned u = ((const unsigned*)startp)[t];
    if (u > 1u) atomicOr(&flags[0], 1);
    float f = ((const float*)startp)[t];
    if (!(f == 0.f || f == 1.f)) atomicOr(&flags[1], 1);
  }
}

__global__ void k_canon(const void* __restrict__ startp, const int* __restrict__ flags,
                        float* __restrict__ start_f) {
  int v32 = flags[0], vf = flags[1];
  int stride = gridDim.x * blockDim.x;
  for (int t = blockIdx.x * blockDim.x + threadIdx.x; t < TT; t += stride) {
    bool s;
    if (v32 == 0)     s = ((const unsigned*)startp)[t] != 0u;
    else if (vf == 0) s = ((const float*)startp)[t] != 0.f;
    else              s = ((const unsigned char*)startp)[t] != 0;
    start_f[t] = s ? 1.f : 0.f;
  }
}

// ---------------------------------------------------------------------------
// Weight conversions (unchanged)
// ---------------------------------------------------------------------------
__global__ __launch_bounds__(256) void k_cvtbig(
    const float* __restrict__ s0, const float* __restrict__ s1, const float* __restrict__ s2,
    unsigned short* __restrict__ d0, unsigned short* __restrict__ d1,
    unsigned short* __restrict__ d2, int n) {
  int i = (blockIdx.x * 256 + threadIdx.x) * 8;
  const float* s; unsigned short* d;
  if (i < n)            { s = s0; d = d0; }
  else if (i < 2 * n)   { s = s1; d = d1; i -= n; }
  else if (i < 3 * n)   { s = s2; d = d2; i -= 2 * n; }
  else return;
  float4 a = *(const float4*)(s + i);
  float4 b = *(const float4*)(s + i + 4);
  float vals[8] = {a.x, a.y, a.z, a.w, b.x, b.y, b.z, b.w};
  bf16x8 t;
#pragma unroll
  for (int j = 0; j < 8; j++) t[j] = (short)f2bf(vals[j]);
  *(bf16x8*)(d + i) = t;
}

__global__ __launch_bounds__(256) void k_cvtproj(
    const float* __restrict__ Wk, const float* __restrict__ Wq, const float* __restrict__ Wv,
    unsigned short* __restrict__ wh, unsigned short* __restrict__ wl) {
  int t8 = blockIdx.x * 256 + threadIdx.x;
  if (t8 >= NBLK * 48 * 256 / 8) return;
  int e = t8 * 8;
  int b = e / (48 * 256);
  int rem = e - b * 48 * 256;
  int o = rem / (16 * 256);
  int nr = rem - o * 16 * 256;
  const float* src = (o == 0 ? Wk : o == 1 ? Wq : Wv) + b * 16 * 256 + nr;
  float4 a = *(const float4*)src;
  float4 c = *(const float4*)(src + 4);
  float vals[8] = {a.x, a.y, a.z, a.w, c.x, c.y, c.z, c.w};
  bf16x8 th, tl;
#pragma unroll
  for (int j = 0; j < 8; j++) {
    unsigned short h = f2bf(vals[j]);
    th[j] = (short)h;
    tl[j] = (short)f2bf(vals[j] - bf2f(h));
  }
  *(bf16x8*)(wh + e) = th;
  *(bf16x8*)(wl + e) = tl;
}

// Wm1 [NB][256][16] -> hi/lo [NB][256][32] zero-padded in k (16..31 = 0)
__global__ __launch_bounds__(256) void k_cvtm1(
    const float* __restrict__ Wm1,
    unsigned short* __restrict__ h, unsigned short* __restrict__ l) {
  int row = blockIdx.x * 256 + threadIdx.x;
  if (row >= NBLK * 256) return;
  const float* s = Wm1 + row * 16;
  bf16x8 th0, tl0, th1, tl1, z;
#pragma unroll
  for (int j = 0; j < 8; j++) {
    float v0 = s[j], v1 = s[j + 8];
    unsigned short h0 = f2bf(v0), h1 = f2bf(v1);
    th0[j] = (short)h0; tl0[j] = (short)f2bf(v0 - bf2f(h0));
    th1[j] = (short)h1; tl1[j] = (short)f2bf(v1 - bf2f(h1));
    z[j] = 0;
  }
  unsigned short* dh = h + row * 32;
  unsigned short* dl = l + row * 32;
  *(bf16x8*)(dh) = th0;  *(bf16x8*)(dh + 8) = th1;
  *(bf16x8*)(dh + 16) = z; *(bf16x8*)(dh + 24) = z;
  *(bf16x8*)(dl) = tl0;  *(bf16x8*)(dl + 8) = tl1;
  *(bf16x8*)(dl + 16) = z; *(bf16x8*)(dl + 24) = z;
}

// ---------------------------------------------------------------------------
// Fused MFMA projection + per-chunk tails (64-row blocks == scan chunks).
//   part 1 (k_proj2 proven): k,q,v via split-bf16 MFMA from LDS-staged x
//   part 2: tails of this chunk computed from k,v kept in LDS (reuses xh)
// ---------------------------------------------------------------------------
__global__ __launch_bounds__(256) void k_projt(
    const float* __restrict__ x,
    const unsigned short* __restrict__ wh, const unsigned short* __restrict__ wl,
    const float* __restrict__ bv, const float* __restrict__ start_f,
    float* __restrict__ kout, float* __restrict__ qout, float* __restrict__ vout,
    float* __restrict__ tails_s, float* __restrict__ tails_zs,
    float* __restrict__ tails_flag) {
  __shared__ unsigned short xh[64 * 256];   // 32 KB swizzled; later kc/vc overlay
  __shared__ unsigned short xl[64 * 256];   // 32 KB swizzled
  __shared__ float stc[CH];
  __shared__ int lsS;
  float* kc = (float*)xh;                   // [64][16] overlay after MFMA
  float* vc = kc + 64 * 16;                 // [64][16]

  int tid = threadIdx.x, wg = blockIdx.x;
  size_t rbase = (size_t)wg * 64;
  const float* xs = x + rbase * DD;
#pragma unroll
  for (int i = 0; i < 8; i++) {
    int idx = tid + i * 256;
    int row = idx >> 5, c8 = idx & 31;
    const float* p = xs + row * DD + c8 * 8;
    float4 a = *(const float4*)p;
    float4 b = *(const float4*)(p + 4);
    float vals[8] = {a.x, a.y, a.z, a.w, b.x, b.y, b.z, b.w};
    bf16x8 th, tl;
#pragma unroll
    for (int j = 0; j < 8; j++) {
      unsigned short h = f2bf(vals[j]);
      th[j] = (short)h;
      tl[j] = (short)f2bf(vals[j] - bf2f(h));
    }
    int off = row * 512 + ((c8 * 16) ^ ((row & 7) << 4));
    *(bf16x8*)((char*)xh + off) = th;
    *(bf16x8*)((char*)xl + off) = tl;
  }
  if (tid < CH) stc[tid] = start_f[wg * CH + tid];
  __syncthreads();

  int lane = tid & 63, wv = tid >> 6, lg = lane >> 4, lr = lane & 15;
  int r = wv * 16 + lr;
  f32x4 acc[3];
#pragma unroll
  for (int o = 0; o < 3; o++) acc[o] = (f32x4){0.f, 0.f, 0.f, 0.f};

#pragma unroll
  for (int kk = 0; kk < 8; kk++) {
    int kbyte = kk * 64 + lg * 16;
    int off = r * 512 + (kbyte ^ ((r & 7) << 4));
    bf16x8 ah = *(bf16x8*)((char*)xh + off);
    bf16x8 al = *(bf16x8*)((char*)xl + off);
#pragma unroll
    for (int o = 0; o < 3; o++) {
      bf16x8 bh = *(const bf16x8*)((const char*)wh + (o * 16 + lr) * 512 + kbyte);
      bf16x8 bl = *(const bf16x8*)((const char*)wl + (o * 16 + lr) * 512 + kbyte);
      acc[o] = __builtin_amdgcn_mfma_f32_16x16x32_bf16(ah, bh, acc[o], 0, 0, 0);
      acc[o] = __builtin_amdgcn_mfma_f32_16x16x32_bf16(al, bh, acc[o], 0, 0, 0);
      acc[o] = __builtin_amdgcn_mfma_f32_16x16x32_bf16(ah, bl, acc[o], 0, 0, 0);
    }
  }
  __syncthreads();   // all MFMA LDS reads done; xh may now be overlaid

  float bvv = bv[lr];
#pragma unroll
  for (int rg = 0; rg < 4; rg++) {
    int rl = wv * 16 + lg * 4 + rg;
    size_t g = rbase + rl;
    float kvl = phi_f(acc[0][rg]);
    float vvl = acc[2][rg] + bvv;
    kout[g * KV + lr] = kvl;
    qout[g * KV + lr] = phi_f(acc[1][rg]);
    vout[g * KV + lr] = vvl;
    kc[rl * KV + lr] = kvl;
    vc[rl * KV + lr] = vvl;
  }
  // last-start index via wave-0 ballot
  if (tid < 64) {
    unsigned long long mask = __ballot(stc[tid] != 0.f);
    if (tid == 0) lsS = mask ? (63 - __builtin_clzll(mask)) : -1;
  }
  __syncthreads();
  int ls = lsS;
  int t0 = ls < 0 ? 0 : ls;
  // tails_s: thread = (i,j)
  {
    int i = tid >> 4, j = tid & 15;
    float s = 0.f;
    for (int t = t0; t < CH; t++) s += kc[t * KV + i] * vc[t * KV + j];
    tails_s[(size_t)wg * 256 + tid] = s;
  }
  // tails_zs: wave-0 shuffle reduce of row k-sums over [t0,64)
  if (tid < 64) {
    float ks = 0.f;
    if (tid >= t0) {
#pragma unroll
      for (int i = 0; i < KV; i++) ks += kc[tid * KV + i];
    }
#pragma unroll
    for (int m = 1; m < 64; m <<= 1) ks += __shfl_xor(ks, m);
    if (tid == 0) {
      tails_zs[wg] = ks;
      tails_flag[wg] = (ls >= 0) ? 1.f : 0.f;
    }
  }
}

// ---------------------------------------------------------------------------
// Attention core (S stride 65: conflict-free PV reads)
// ---------------------------------------------------------------------------
#define SP 65
__global__ __launch_bounds__(256) void k_att(
    const float* __restrict__ q, const float* __restrict__ k,
    const float* __restrict__ v, const float* __restrict__ start_f,
    const float* __restrict__ tails_s, const float* __restrict__ tails_zs,
    const float* __restrict__ tails_flag,
    const float* __restrict__ s0, const float* __restrict__ z0,
    float* __restrict__ att) {
  __shared__ float qc[CH * KV], kc[CH * KV], vc[CH * KV], stc[CH];
  __shared__ float S[CH * SP];
  __shared__ float carry[256];
  __shared__ float ksum[CH], zsl[CH], qsum[CH];
  __shared__ int ns[CH];
  __shared__ float czs_s;
  int c = blockIdx.x, tid = threadIdx.x;
  size_t base = (size_t)c * CH * KV;
  for (int u = tid; u < CH * KV; u += 256) {
    qc[u] = q[base + u]; kc[u] = k[base + u]; vc[u] = v[base + u];
  }
  if (tid < CH) stc[tid] = start_f[c * CH + tid];
  __syncthreads();
  if (tid < CH) {
    int cnt = 0;
    for (int u = 0; u <= tid; u++) cnt += (stc[u] != 0.f);
    ns[tid] = cnt;
    float ks = 0.f, qs = 0.f;
    for (int i = 0; i < KV; i++) { ks += kc[tid * KV + i]; qs += qc[tid * KV + i]; }
    ksum[tid] = ks; qsum[tid] = qs;
  }
  __syncthreads();
  if (tid < CH) {
    float acc = 0.f;
    for (int u = tid; u >= 0; u--) { acc += ksum[u]; if (stc[u] != 0.f) break; }
    zsl[tid] = acc;
  }
  {
    float accs = 0.f, aczs = 0.f;
    int cc = c - 1;
    for (;;) {
      if (cc < 0) {
        accs += s0[tid];
        if (tid == 0) { float z = 0.f; for (int i = 0; i < KV; i++) z += z0[i]; aczs += z; }
        break;
      }
      float fl = tails_flag[cc];
      accs += tails_s[(size_t)cc * 256 + tid];
      if (tid == 0) aczs += tails_zs[cc];
      if (fl != 0.f) break;
      cc--;
    }
    carry[tid] = accs;
    if (tid == 0) czs_s = aczs;
  }
  __syncthreads();
  {
    int t = tid >> 2, g = tid & 3;
    for (int u = 0; u < 16; u++) {
      int tp = g * 16 + u;
      float val = 0.f;
      if (tp <= t && ns[tp] == ns[t]) {
        float dot = 0.f;
        for (int i = 0; i < KV; i++) dot += qc[t * KV + i] * kc[tp * KV + i];
        val = dot;
      }
      S[t * SP + tp] = val;
    }
  }
  __syncthreads();
  float czs = czs_s;
  int j = tid & 15, tr = tid >> 4;
  for (int p = 0; p < 4; p++) {
    int t = p * 16 + tr;
    float numer = 0.f;
    for (int tp = 0; tp < CH; tp++) numer += S[t * SP + tp] * vc[tp * KV + j];
    float zs = zsl[t];
    if (ns[t] == 0) {
      float cn = 0.f;
      for (int i = 0; i < KV; i++) cn += qc[t * KV + i] * carry[i * KV + j];
      numer += cn;
      zs += czs;
    }
    float denom = fmaxf(zs * qsum[t], 1e-6f);
    att[base + t * KV + j] = numer / denom;
  }
}

// ---------------------------------------------------------------------------
// All-MFMA MLP + skip + LayerNorm. 4 waves (256 thr), wave owns 64x64
// (r3-proven shape), MFMA stage A, VGPR headroom for pipelining.
// ---------------------------------------------------------------------------
#define A1S 40   // padded row stride (shorts) for att hi/lo staging
template<int WY, int WX>
__global__ __launch_bounds__(256, 2) void k_mlp5(
    const float* __restrict__ att, const float* __restrict__ xsrc,
    const unsigned short* __restrict__ wm1h, const unsigned short* __restrict__ wm1l,
    const float* __restrict__ bm1,
    const unsigned short* __restrict__ Wm2b, const float* __restrict__ bm2,
    const unsigned short* __restrict__ Wm3b, const float* __restrict__ bm3,
    const unsigned short* __restrict__ Wskb, const float* __restrict__ bsk,
    const float* __restrict__ lnw, const float* __restrict__ lnb,
    float* __restrict__ yout, float* __restrict__ xnext) {
  __shared__ unsigned short hb[64 * 256];        // 32KB swizzled bf16 (h1 then h2)
  __shared__ __align__(16) char uni[64 * A1S * 4];  // aoh/aol, later LN scratch
  unsigned short* aoh = (unsigned short*)uni;    // [64][A1S]
  unsigned short* aol = aoh + 64 * A1S;
  float* redS = (float*)uni;                     // [256]
  float* redQ = redS + 256;
  float* mrow = redQ + 256;                      // [64]
  float* irow = mrow + 64;

  int tid = threadIdx.x, wg = blockIdx.x;
  size_t rbase = (size_t)wg * 64;

  // load att -> hi/lo, K zero-padded 16..31
  for (int idx = tid; idx < 64 * 32; idx += 256) {
    int row = idx >> 5, col = idx & 31;
    float v = (col < 16) ? att[(rbase + row) * KV + col] : 0.f;
    unsigned short h = f2bf(v);
    aoh[row * A1S + col] = h;
    aol[row * A1S + col] = f2bf(v - bf2f(h));
  }
  __syncthreads();

  int lane = tid & 63, wv = tid >> 6, lg = lane >> 4, lr = lane & 15;
  int nc0 = wv * 64;          // wave's 64-column slice

  f32x4 acc[4][4];
#pragma unroll
  for (int a = 0; a < 4; a++)
#pragma unroll
    for (int b = 0; b < 4; b++) acc[a][b] = (f32x4){0.f, 0.f, 0.f, 0.f};

  // ---- stage A (MFMA): h1 = lrelu(att@Wm1^T + bm1)
  {
    bf16x8 b1h[4], b1l[4];
#pragma unroll
    for (int nt = 0; nt < 4; nt++) {
      int n = nc0 + nt * 16 + lr;
      b1h[nt] = *(const bf16x8*)(wm1h + n * 32 + lg * 8);
      b1l[nt] = *(const bf16x8*)(wm1l + n * 32 + lg * 8);
    }
#pragma unroll
    for (int mt = 0; mt < 4; mt++) {
      int r = mt * 16 + lr;
      bf16x8 ah = *(bf16x8*)(aoh + r * A1S + lg * 8);
      bf16x8 al = *(bf16x8*)(aol + r * A1S + lg * 8);
#pragma unroll
      for (int nt = 0; nt < 4; nt++) {
        acc[mt][nt] = __builtin_amdgcn_mfma_f32_16x16x32_bf16(ah, b1h[nt], acc[mt][nt], 0, 0, 0);
        acc[mt][nt] = __builtin_amdgcn_mfma_f32_16x16x32_bf16(al, b1h[nt], acc[mt][nt], 0, 0, 0);
        acc[mt][nt] = __builtin_amdgcn_mfma_f32_16x16x32_bf16(ah, b1l[nt], acc[mt][nt], 0, 0, 0);
      }
    }
  }
  __syncthreads();   // aoh/aol reads done (uni reused for LN later)
  {
    float bm1v[4];
#pragma unroll
    for (int nt = 0; nt < 4; nt++) bm1v[nt] = bm1[nc0 + nt * 16 + lr];
#pragma unroll
    for (int mt = 0; mt < 4; mt++)
#pragma unroll
      for (int nt = 0; nt < 4; nt++)
#pragma unroll
        for (int rg = 0; rg < 4; rg++) {
          int r = mt * 16 + lg * 4 + rg;
          int cc = nc0 + nt * 16 + lr;
          *(unsigned short*)((char*)hb + r * 512 + ((cc * 2) ^ ((r & 7) << 4))) =
              f2bf(lrelu_f(acc[mt][nt][rg] + bm1v[nt]));
        }
  }
  __syncthreads();

  // ---- stage B (MFMA): h2 = lrelu(h1@Wm2^T+bm2)
#pragma unroll
  for (int a = 0; a < 4; a++)
#pragma unroll
    for (int b = 0; b < 4; b++) acc[a][b] = (f32x4){0.f, 0.f, 0.f, 0.f};
#pragma unroll
  for (int kk = 0; kk < 8; kk++) {
    int kbyte = kk * 64 + lg * 16;
    bf16x8 bfr[4];
#pragma unroll
    for (int nt = 0; nt < 4; nt++) {
      int n = nc0 + nt * 16 + lr;
      bfr[nt] = *(const bf16x8*)((const char*)Wm2b + n * 512 + kbyte);
    }
#pragma unroll
    for (int mt = 0; mt < 4; mt++) {
      int r = mt * 16 + lr;
      bf16x8 af = *(bf16x8*)((char*)hb + r * 512 + (kbyte ^ ((r & 7) << 4)));
#pragma unroll
      for (int nt = 0; nt < 4; nt++)
        acc[mt][nt] = __builtin_amdgcn_mfma_f32_16x16x32_bf16(af, bfr[nt], acc[mt][nt], 0, 0, 0);
    }
  }
  __syncthreads();   // all reads of h1 complete before overwrite
  {
    float bm2v[4];
#pragma unroll
    for (int nt = 0; nt < 4; nt++) bm2v[nt] = bm2[nc0 + nt * 16 + lr];
#pragma unroll
    for (int mt = 0; mt < 4; mt++)
#pragma unroll
      for (int nt = 0; nt < 4; nt++)
#pragma unroll
        for (int rg = 0; rg < 4; rg++) {
          int r = mt * 16 + lg * 4 + rg;
          int cc = nc0 + nt * 16 + lr;
          *(unsigned short*)((char*)hb + r * 512 + ((cc * 2) ^ ((r & 7) << 4))) =
              f2bf(lrelu_f(acc[mt][nt][rg] + bm2v[nt]));
        }
  }
  __syncthreads();

  // ---- stage C: hf = h2@Wm3^T + x@Wsk^T
  f32x4 acc2[4][4];
#pragma unroll
  for (int a = 0; a < 4; a++)
#pragma unroll
    for (int b = 0; b < 4; b++) acc2[a][b] = (f32x4){0.f, 0.f, 0.f, 0.f};
  const float* xrow = xsrc + rbase * DD;
#pragma unroll
  for (int kk = 0; kk < 8; kk++) {
    int kbyte = kk * 64 + lg * 16;
    int kf = kk * 32 + lg * 8;
    bf16x8 b3[4], bs[4];
#pragma unroll
    for (int nt = 0; nt < 4; nt++) {
      int n = nc0 + nt * 16 + lr;
      b3[nt] = *(const bf16x8*)((const char*)Wm3b + n * 512 + kbyte);
      bs[nt] = *(const bf16x8*)((const char*)Wskb + n * 512 + kbyte);
    }
#pragma unroll
    for (int mt = 0; mt < 4; mt++) {
      int r = mt * 16 + lr;
      bf16x8 a2 = *(bf16x8*)((char*)hb + r * 512 + (kbyte ^ ((r & 7) << 4)));
#pragma unroll
      for (int nt = 0; nt < 4; nt++)
        acc2[mt][nt] = __builtin_amdgcn_mfma_f32_16x16x32_bf16(a2, b3[nt], acc2[mt][nt], 0, 0, 0);
      const float* xp = xrow + r * DD + kf;
      float4 x0 = *(const float4*)xp;
      float4 x1 = *(const float4*)(xp + 4);
      bf16x8 xv;
      xv[0] = (short)f2bf(x0.x); xv[1] = (short)f2bf(x0.y);
      xv[2] = (short)f2bf(x0.z); xv[3] = (short)f2bf(x0.w);
      xv[4] = (short)f2bf(x1.x); xv[5] = (short)f2bf(x1.y);
      xv[6] = (short)f2bf(x1.z); xv[7] = (short)f2bf(x1.w);
#pragma unroll
      for (int nt = 0; nt < 4; nt++)
        acc2[mt][nt] = __builtin_amdgcn_mfma_f32_16x16x32_bf16(xv, bs[nt], acc2[mt][nt], 0, 0, 0);
    }
  }
#pragma unroll
  for (int nt = 0; nt < 4; nt++) {
    int cc = nc0 + nt * 16 + lr;
    float bb = bm3[cc] + bsk[cc];
#pragma unroll
    for (int mt = 0; mt < 4; mt++)
#pragma unroll
      for (int rg = 0; rg < 4; rg++) acc2[mt][nt][rg] += bb;
  }

  // ---- LayerNorm stats in registers
#pragma unroll
  for (int mt = 0; mt < 4; mt++)
#pragma unroll
    for (int rg = 0; rg < 4; rg++) {
      float s = 0.f, q = 0.f;
#pragma unroll
      for (int nt = 0; nt < 4; nt++) {
        float v = acc2[mt][nt][rg];
        s += v; q += v * v;
      }
#pragma unroll
      for (int m = 1; m < 16; m <<= 1) {
        s += __shfl_xor(s, m);
        q += __shfl_xor(q, m);
      }
      if (lr == 0) {
        int r = mt * 16 + lg * 4 + rg;
        redS[wv * 64 + r] = s;
        redQ[wv * 64 + r] = q;
      }
    }
  __syncthreads();
  if (tid < 64) {
    float s = 0.f, q = 0.f;
#pragma unroll
    for (int w = 0; w < 4; w++) { s += redS[w * 64 + tid]; q += redQ[w * 64 + tid]; }
    float m = s * (1.f / 256.f);
    float var = q * (1.f / 256.f) - m * m;
    mrow[tid] = m;
    irow[tid] = rsqrtf(var + 1e-5f);
  }
  __syncthreads();

  // ---- normalize + store (f32 coalesced only)
  {
    float lnwv[4], lnbv[4];
#pragma unroll
    for (int nt = 0; nt < 4; nt++) {
      int cc = nc0 + nt * 16 + lr;
      lnwv[nt] = lnw[cc]; lnbv[nt] = lnb[cc];
    }
#pragma unroll
    for (int mt = 0; mt < 4; mt++)
#pragma unroll
      for (int rg = 0; rg < 4; rg++) {
        int r = mt * 16 + lg * 4 + rg;
        float m = mrow[r], is = irow[r];
        size_t gr = (rbase + r) * DD;
#pragma unroll
        for (int nt = 0; nt < 4; nt++) {
          int cc = nc0 + nt * 16 + lr;
          float y = (acc2[mt][nt][rg] - m) * is * lnwv[nt] + lnbv[nt];
          if (WY) yout[gr + cc] = y;
          if (WX) xnext[gr + cc] = xsrc[gr + cc] + y;
        }
      }
  }
}

// ---------------------------------------------------------------------------
extern "C" void kernel_launch(void* const* d_in, const int* in_sizes, int n_in,
                              void* d_out, int out_size, void* d_ws, size_t ws_size,
                              hipStream_t stream) {
  const float* x_in = (const float*)d_in[0];
  const void*  startp = d_in[1];
  const float* s0  = (const float*)d_in[2];
  const float* z0  = (const float*)d_in[3];
  const float* Wk  = (const float*)d_in[4];
  const float* Wq  = (const float*)d_in[5];
  const float* Wv  = (const float*)d_in[6];
  const float* bv  = (const float*)d_in[7];
  const float* Wsk = (const float*)d_in[8];
  const float* bsk = (const float*)d_in[9];
  const float* Wm1 = (const float*)d_in[10];
  const float* bm1 = (const float*)d_in[11];
  const float* Wm2 = (const float*)d_in[12];
  const float* bm2 = (const float*)d_in[13];
  const float* Wm3 = (const float*)d_in[14];
  const float* bm3 = (const float*)d_in[15];
  const float* lnw = (const float*)d_in[16];
  const float* lnb = (const float*)d_in[17];
  float* yout = (float*)d_out;

  float* ws = (float*)d_ws;
  int*   flags   = (int*)d_ws;
  float* start_f = ws + 16;
  float* kbuf    = start_f + TT;
  float* qbuf    = kbuf + (size_t)TT * KV;
  float* vbuf    = qbuf + (size_t)TT * KV;
  float* abuf    = vbuf + (size_t)TT * KV;
  float* ts      = abuf + (size_t)TT * KV;
  float* tz      = ts + (size_t)NCH * 256;
  float* tf      = tz + NCH;
  float* xcur    = tf + NCH;                                // T*D f32
  unsigned short* wm2b = (unsigned short*)(xcur + (size_t)TT * DD);
  unsigned short* wm3b = wm2b + (size_t)NBLK * HH * HH;
  unsigned short* wskb = wm3b + (size_t)NBLK * HH * HH;
  unsigned short* wpjh = wskb + (size_t)NBLK * HH * DD;     // [b][48][256] hi
  unsigned short* wpjl = wpjh + (size_t)NBLK * 48 * DD;     // [b][48][256] lo
  unsigned short* wm1h = wpjl + (size_t)NBLK * 48 * DD;     // [b][256][32]
  unsigned short* wm1l = wm1h + (size_t)NBLK * HH * 32;

  hipMemsetAsync(d_ws, 0, 64, stream);
  k_detect<<<64, 256, 0, stream>>>(startp, flags);
  k_canon<<<256, 256, 0, stream>>>(startp, flags, start_f);

  k_cvtbig<<<192, 256, 0, stream>>>(Wm2, Wm3, Wsk, wm2b, wm3b, wskb, NBLK * HH * HH);
  k_cvtproj<<<12, 256, 0, stream>>>(Wk, Wq, Wv, wpjh, wpjl);
  k_cvtm1<<<2, 256, 0, stream>>>(Wm1, wm1h, wm1l);

  const float* xs = x_in;
  for (int b = 0; b < NBLK; b++) {
    k_projt<<<TT / 64, 256, 0, stream>>>(xs,
        wpjh + (size_t)b * 48 * DD, wpjl + (size_t)b * 48 * DD,
        bv + (size_t)b * KV, start_f, kbuf, qbuf, vbuf, ts, tz, tf);
    k_att<<<NCH, 256, 0, stream>>>(qbuf, kbuf, vbuf, start_f, ts, tz, tf,
        s0 + (size_t)b * 256, z0 + (size_t)b * KV, abuf);
    if (b == 0) {
      k_mlp5<0, 1><<<TT / 64, 256, 0, stream>>>(abuf, xs,
          wm1h + (size_t)b * HH * 32, wm1l + (size_t)b * HH * 32, bm1 + (size_t)b * HH,
          wm2b + (size_t)b * HH * HH, bm2 + (size_t)b * HH,
          wm3b + (size_t)b * HH * HH, bm3 + (size_t)b * HH,
          wskb + (size_t)b * HH * DD, bsk + (size_t)b * HH,
          lnw + (size_t)b * HH, lnb + (size_t)b * HH, yout, xcur);
    } else {
      k_mlp5<1, 0><<<TT / 64, 256, 0, stream>>>(abuf, xs,
          wm1h + (size_t)b * HH * 32, wm1l + (size_t)b * HH * 32, bm1 + (size_t)b * HH,
          wm2b + (size_t)b * HH * HH, bm2 + (size_t)b * HH,
          wm3b + (size_t)b * HH * HH, bm3 + (size_t)b * HH,
          wskb + (size_t)b * HH * DD, bsk + (size_t)b * HH,
          lnw + (size_t)b * HH, lnb + (size_t)b * HH, yout, xcur);
    }
    xs = xcur;
  }
}